// Round 2
// baseline (13526.671 us; speedup 1.0000x reference)
//
#include <hip/hip_runtime.h>
#include <hip/hip_bf16.h>

#define SEQ 2048
#define HEADD 128

// C[M,N] = A[M,K] @ W[N,K]^T + bias[N], optional SiLU. fp32 accumulate.
// 64x64 tile, 256 threads (16x16), 4x4 micro-tile, BK=16, transposed LDS.
template <bool SILU>
__global__ void gemm_kernel(const float* __restrict__ A, const float* __restrict__ W,
                            const float* __restrict__ bias, float* __restrict__ C,
                            int M, int N, int Kd) {
    __shared__ __align__(16) float As[16][72];
    __shared__ __align__(16) float Ws[16][72];
    const int tx = threadIdx.x, ty = threadIdx.y;
    const int tid = ty * 16 + tx;
    const int m0 = blockIdx.y * 64, n0 = blockIdx.x * 64;
    float acc[4][4] = {};
    for (int k0 = 0; k0 < Kd; k0 += 16) {
#pragma unroll
        for (int it = 0; it < 4; ++it) {
            int idx = tid + it * 256;
            int mm = idx >> 4, kk = idx & 15;
            As[kk][mm] = A[(size_t)(m0 + mm) * Kd + k0 + kk];
            Ws[kk][mm] = W[(size_t)(n0 + mm) * Kd + k0 + kk];
        }
        __syncthreads();
#pragma unroll
        for (int kk = 0; kk < 16; ++kk) {
            float4 a4 = *(const float4*)&As[kk][ty * 4];
            float4 b4 = *(const float4*)&Ws[kk][tx * 4];
            float av[4] = {a4.x, a4.y, a4.z, a4.w};
            float bv[4] = {b4.x, b4.y, b4.z, b4.w};
#pragma unroll
            for (int i = 0; i < 4; ++i)
#pragma unroll
                for (int j = 0; j < 4; ++j)
                    acc[i][j] += av[i] * bv[j];
        }
        __syncthreads();
    }
#pragma unroll
    for (int i = 0; i < 4; ++i) {
        int m = m0 + ty * 4 + i;
#pragma unroll
        for (int j = 0; j < 4; ++j) {
            int n = n0 + tx * 4 + j;
            float v = acc[i][j] + bias[n];
            if (SILU) v = v / (1.f + __expf(-v));
            C[(size_t)m * N + n] = v;
        }
    }
}

// In-place RoPE on q (S x 1024, 8 heads) and k (S x 512, 4 heads).
__global__ void rope_kernel(float* __restrict__ qb, float* __restrict__ kb) {
    const int s = blockIdx.x;
    const float t = (float)s;
    for (int p = threadIdx.x; p < 768; p += 256) {
        int idx = p & 63;
        float invf = powf(10000.f, -(float)(2 * idx) / 128.f);
        float ang = t * invf;
        float c = cosf(ang), sn = sinf(ang);
        float* base;
        if (p < 512) {
            int h = p >> 6;
            base = qb + (size_t)s * 1024 + h * 128 + idx;
        } else {
            int h = (p - 512) >> 6;
            base = kb + (size_t)s * 512 + h * 128 + idx;
        }
        float x1 = base[0], x2 = base[64];
        base[0] = x1 * c - x2 * sn;
        base[64] = x2 * c + x1 * sn;
    }
}

// Attention: block = (query i, head h), 256 threads.
// attn[i, h*128+d] = sum_g softmax_j(q_i . k_gj / sqrt(128)) @ v_g   (causal j<=i)
__global__ void attn_kernel(const float* __restrict__ qb, const float* __restrict__ kb,
                            const float* __restrict__ vb, float* __restrict__ attn) {
    const int i = blockIdx.x;
    const int h = blockIdx.y;
    const int tid = threadIdx.x;
    __shared__ float sc[SEQ];
    __shared__ float qrow[HEADD];
    __shared__ float red[256];
    if (tid < 128) qrow[tid] = qb[(size_t)i * 1024 + h * 128 + tid];
    __syncthreads();
    const int n = i + 1;
    const int d = tid & 127, part = tid >> 7;
    float out_acc = 0.f;
    for (int g = 0; g < 4; ++g) {
        const float* kg = kb + g * 128;
        float lmax = -1e30f;
        for (int j = tid; j < n; j += 256) {
            const float4* kr4 = (const float4*)(kg + (size_t)j * 512);
            float dot = 0.f;
#pragma unroll
            for (int dd = 0; dd < 32; ++dd) {
                float4 kx = kr4[dd];
                dot += qrow[dd * 4 + 0] * kx.x + qrow[dd * 4 + 1] * kx.y +
                       qrow[dd * 4 + 2] * kx.z + qrow[dd * 4 + 3] * kx.w;
            }
            dot *= 0.08838834764831845f;  // 1/sqrt(128)
            sc[j] = dot;
            lmax = fmaxf(lmax, dot);
        }
        red[tid] = lmax;
        __syncthreads();
        for (int s2 = 128; s2 > 0; s2 >>= 1) {
            if (tid < s2) red[tid] = fmaxf(red[tid], red[tid + s2]);
            __syncthreads();
        }
        float m = red[0];
        __syncthreads();
        float lsum = 0.f;
        for (int j = tid; j < n; j += 256) {
            float e = __expf(sc[j] - m);
            sc[j] = e;
            lsum += e;
        }
        red[tid] = lsum;
        __syncthreads();
        for (int s2 = 128; s2 > 0; s2 >>= 1) {
            if (tid < s2) red[tid] += red[tid + s2];
            __syncthreads();
        }
        float inv = 1.f / red[0];
        float a = 0.f;
        for (int j = part; j < n; j += 2) a += sc[j] * vb[(size_t)j * 512 + g * 128 + d];
        out_acc += a * inv;
        __syncthreads();  // before next g overwrites sc / red
    }
    red[tid] = out_acc;
    __syncthreads();
    if (tid < 128) attn[(size_t)i * 1024 + h * 128 + tid] = red[tid] + red[tid + 128];
}

extern "C" void kernel_launch(void* const* d_in, const int* in_sizes, int n_in,
                              void* d_out, int out_size, void* d_ws, size_t ws_size,
                              hipStream_t stream) {
    const float* x  = (const float*)d_in[0];
    const float* Wq = (const float*)d_in[1];
    const float* bq = (const float*)d_in[2];
    const float* Wk = (const float*)d_in[3];
    const float* bk = (const float*)d_in[4];
    const float* Wv = (const float*)d_in[5];
    const float* bv = (const float*)d_in[6];
    const float* Wo = (const float*)d_in[7];
    const float* bo = (const float*)d_in[8];
    const float* W1 = (const float*)d_in[9];
    const float* b1 = (const float*)d_in[10];
    const float* W2 = (const float*)d_in[11];
    const float* b2 = (const float*)d_in[12];
    float* out = (float*)d_out;

    float* q_ws    = (float*)d_ws;                       // 2048*1024
    float* k_ws    = q_ws + (size_t)SEQ * 1024;          // 2048*512
    float* v_ws    = k_ws + (size_t)SEQ * 512;           // 2048*512
    float* attn_ws = v_ws + (size_t)SEQ * 512;           // 2048*1024
    float* o_ws    = attn_ws + (size_t)SEQ * 1024;       // 2048*1024
    float* h1_ws   = o_ws + (size_t)SEQ * 1024;          // 2048*4096

    dim3 blk(16, 16);
    // q/k/v projections
    gemm_kernel<false><<<dim3(1024 / 64, SEQ / 64), blk, 0, stream>>>(
        x, Wq, bq, q_ws, SEQ, 1024, 1024);
    gemm_kernel<false><<<dim3(512 / 64, SEQ / 64), blk, 0, stream>>>(
        x, Wk, bk, k_ws, SEQ, 512, 1024);
    gemm_kernel<false><<<dim3(512 / 64, SEQ / 64), blk, 0, stream>>>(
        x, Wv, bv, v_ws, SEQ, 512, 1024);
    // RoPE in place on q,k
    rope_kernel<<<SEQ, 256, 0, stream>>>(q_ws, k_ws);
    // attention
    attn_kernel<<<dim3(SEQ, 8), 256, 0, stream>>>(q_ws, k_ws, v_ws, attn_ws);
    // output projection
    gemm_kernel<false><<<dim3(1024 / 64, SEQ / 64), blk, 0, stream>>>(
        attn_ws, Wo, bo, o_ws, SEQ, 1024, 1024);
    // MLP
    gemm_kernel<true><<<dim3(4096 / 64, SEQ / 64), blk, 0, stream>>>(
        o_ws, W1, b1, h1_ws, SEQ, 4096, 1024);
    gemm_kernel<false><<<dim3(4096 / 64, SEQ / 64), blk, 0, stream>>>(
        h1_ws, W2, b2, out, SEQ, 4096, 4096);
}

// Round 3
// 3701.834 us; speedup vs baseline: 3.6540x; 3.6540x over previous
//
#include <hip/hip_runtime.h>
#include <hip/hip_bf16.h>

#define SEQ 2048
#define TQ 64
#define TJ 64

// C[M,N] = A[M,K] @ W[N,K]^T + bias[N], optional SiLU. fp32 accumulate.
// 64x64 tile, 256 threads (16x16), 4x4 micro-tile, BK=16, transposed LDS.
template <bool SILU>
__global__ void gemm_kernel(const float* __restrict__ A, const float* __restrict__ W,
                            const float* __restrict__ bias, float* __restrict__ C,
                            int M, int N, int Kd) {
    __shared__ __align__(16) float As[16][72];
    __shared__ __align__(16) float Ws[16][72];
    const int tx = threadIdx.x, ty = threadIdx.y;
    const int tid = ty * 16 + tx;
    const int m0 = blockIdx.y * 64, n0 = blockIdx.x * 64;
    float acc[4][4] = {};
    for (int k0 = 0; k0 < Kd; k0 += 16) {
#pragma unroll
        for (int it = 0; it < 4; ++it) {
            int idx = tid + it * 256;
            int mm = idx >> 4, kk = idx & 15;
            As[kk][mm] = A[(size_t)(m0 + mm) * Kd + k0 + kk];
            Ws[kk][mm] = W[(size_t)(n0 + mm) * Kd + k0 + kk];
        }
        __syncthreads();
#pragma unroll
        for (int kk = 0; kk < 16; ++kk) {
            float4 a4 = *(const float4*)&As[kk][ty * 4];
            float4 b4 = *(const float4*)&Ws[kk][tx * 4];
            float av[4] = {a4.x, a4.y, a4.z, a4.w};
            float bv[4] = {b4.x, b4.y, b4.z, b4.w};
#pragma unroll
            for (int i = 0; i < 4; ++i)
#pragma unroll
                for (int j = 0; j < 4; ++j)
                    acc[i][j] += av[i] * bv[j];
        }
        __syncthreads();
    }
#pragma unroll
    for (int i = 0; i < 4; ++i) {
        int m = m0 + ty * 4 + i;
#pragma unroll
        for (int j = 0; j < 4; ++j) {
            int n = n0 + tx * 4 + j;
            float v = acc[i][j] + bias[n];
            if (SILU) v = v / (1.f + __expf(-v));
            C[(size_t)m * N + n] = v;
        }
    }
}

// In-place RoPE on q (S x 1024, 8 heads) and k (S x 512, 4 heads).
__global__ void rope_kernel(float* __restrict__ qb, float* __restrict__ kb) {
    const int s = blockIdx.x;
    const float t = (float)s;
    for (int p = threadIdx.x; p < 768; p += 256) {
        int idx = p & 63;
        float invf = powf(10000.f, -(float)(2 * idx) / 128.f);
        float ang = t * invf;
        float c = cosf(ang), sn = sinf(ang);
        float* base;
        if (p < 512) {
            int h = p >> 6;
            base = qb + (size_t)s * 1024 + h * 128 + idx;
        } else {
            int h = (p - 512) >> 6;
            base = kb + (size_t)s * 512 + h * 128 + idx;
        }
        float x1 = base[0], x2 = base[64];
        base[0] = x1 * c - x2 * sn;
        base[64] = x2 * c + x1 * sn;
    }
}

// Flash attention, one block = (64-query tile i0, head h, group g), 256 threads (16x16).
// Writes normalized per-group output to part[g][s][h*128+d].
__global__ __launch_bounds__(256) void flash_attn_kernel(
    const float* __restrict__ qb, const float* __restrict__ kb,
    const float* __restrict__ vb, float* __restrict__ part) {
    const int i0 = blockIdx.x * TQ;
    const int h = blockIdx.y;
    const int g = blockIdx.z;
    const int tx = threadIdx.x, ty = threadIdx.y;
    const int tid = ty * 16 + tx;

    __shared__ __align__(16) float Qs[16][72];
    __shared__ __align__(16) float Ks[16][72];
    __shared__ __align__(16) float Ss[TQ][65];   // scores, then P
    __shared__ __align__(16) float Vs[TJ][132];
    __shared__ float redm[4][64], redl[4][64];
    __shared__ float m_sh[64], l_sh[64], al_sh[64];

    if (tid < 64) { m_sh[tid] = -1e30f; l_sh[tid] = 0.f; }

    float acc[4][8] = {};  // rows q=ty*4+i ; cols d = tx*4+r (n<4) and 64+tx*4+r (n>=4)
    const int nt = blockIdx.x + 1;  // j-tiles: j0 = 0..i0 step 64
    for (int jt = 0; jt < nt; ++jt) {
        const int j0 = jt * TJ;
        // ---- S = Q K^T (gemm-style, BK=16 chunks staged from global) ----
        float sacc[4][4] = {};
        for (int k0 = 0; k0 < 128; k0 += 16) {
#pragma unroll
            for (int it = 0; it < 4; ++it) {
                int idx = tid + it * 256;
                int mm = idx >> 4, kk = idx & 15;
                Qs[kk][mm] = qb[(size_t)(i0 + mm) * 1024 + h * 128 + k0 + kk];
                Ks[kk][mm] = kb[(size_t)(j0 + mm) * 512 + g * 128 + k0 + kk];
            }
            __syncthreads();
#pragma unroll
            for (int kk = 0; kk < 16; ++kk) {
                float4 a4 = *(const float4*)&Qs[kk][ty * 4];
                float4 b4 = *(const float4*)&Ks[kk][tx * 4];
                float av[4] = {a4.x, a4.y, a4.z, a4.w};
                float bv[4] = {b4.x, b4.y, b4.z, b4.w};
#pragma unroll
                for (int i = 0; i < 4; ++i)
#pragma unroll
                    for (int j = 0; j < 4; ++j)
                        sacc[i][j] += av[i] * bv[j];
            }
            __syncthreads();
        }
        // ---- stage V tile ----
#pragma unroll
        for (int it = 0; it < 8; ++it) {
            int idx = tid + it * 256;           // 2048 float4 = 64 rows x 32 chunks
            int row = idx >> 5, c4 = idx & 31;
            *(float4*)&Vs[row][c4 * 4] =
                *(const float4*)&vb[(size_t)(j0 + row) * 512 + g * 128 + c4 * 4];
        }
        // ---- masked, scaled scores to LDS ----
#pragma unroll
        for (int i = 0; i < 4; ++i) {
            int qg = i0 + ty * 4 + i;
#pragma unroll
            for (int jj = 0; jj < 4; ++jj) {
                int jg = j0 + tx * 4 + jj;
                float v = sacc[i][jj] * 0.08838834764831845f;
                Ss[ty * 4 + i][tx * 4 + jj] = (jg <= qg) ? v : -1e30f;
            }
        }
        __syncthreads();
        // ---- row max partials (wave w covers 16 cols) ----
        {
            int row = tid & 63, prt = tid >> 6;
            float mx = -1e30f;
#pragma unroll
            for (int jj = 0; jj < 16; ++jj) mx = fmaxf(mx, Ss[row][prt * 16 + jj]);
            redm[prt][row] = mx;
        }
        __syncthreads();
        if (tid < 64) {
            float mo = m_sh[tid];
            float mn = fmaxf(fmaxf(redm[0][tid], redm[1][tid]),
                             fmaxf(redm[2][tid], redm[3][tid]));
            mn = fmaxf(mo, mn);
            m_sh[tid] = mn;
            al_sh[tid] = __expf(mo - mn);  // first tile: exp(-1e30-mn)=0
        }
        __syncthreads();
        // ---- P = exp(S - m), row-sum partials ----
        {
            int row = tid & 63, prt = tid >> 6;
            float mrow = m_sh[row];
            float ps = 0.f;
#pragma unroll
            for (int jj = 0; jj < 16; ++jj) {
                float e = __expf(Ss[row][prt * 16 + jj] - mrow);
                Ss[row][prt * 16 + jj] = e;
                ps += e;
            }
            redl[prt][row] = ps;
        }
        __syncthreads();
        if (tid < 64) {
            l_sh[tid] = l_sh[tid] * al_sh[tid] +
                        redl[0][tid] + redl[1][tid] + redl[2][tid] + redl[3][tid];
        }
        // ---- rescale O, accumulate P·V ----
        float alpha_i[4];
#pragma unroll
        for (int i = 0; i < 4; ++i) alpha_i[i] = al_sh[ty * 4 + i];
#pragma unroll
        for (int i = 0; i < 4; ++i)
#pragma unroll
            for (int n = 0; n < 8; ++n) acc[i][n] *= alpha_i[i];
        for (int jj = 0; jj < TJ; ++jj) {
            float p0 = Ss[ty * 4 + 0][jj];
            float p1 = Ss[ty * 4 + 1][jj];
            float p2 = Ss[ty * 4 + 2][jj];
            float p3 = Ss[ty * 4 + 3][jj];
            float4 va = *(const float4*)&Vs[jj][tx * 4];
            float4 vb4 = *(const float4*)&Vs[jj][64 + tx * 4];
            acc[0][0] += p0 * va.x;  acc[0][1] += p0 * va.y;
            acc[0][2] += p0 * va.z;  acc[0][3] += p0 * va.w;
            acc[0][4] += p0 * vb4.x; acc[0][5] += p0 * vb4.y;
            acc[0][6] += p0 * vb4.z; acc[0][7] += p0 * vb4.w;
            acc[1][0] += p1 * va.x;  acc[1][1] += p1 * va.y;
            acc[1][2] += p1 * va.z;  acc[1][3] += p1 * va.w;
            acc[1][4] += p1 * vb4.x; acc[1][5] += p1 * vb4.y;
            acc[1][6] += p1 * vb4.z; acc[1][7] += p1 * vb4.w;
            acc[2][0] += p2 * va.x;  acc[2][1] += p2 * va.y;
            acc[2][2] += p2 * va.z;  acc[2][3] += p2 * va.w;
            acc[2][4] += p2 * vb4.x; acc[2][5] += p2 * vb4.y;
            acc[2][6] += p2 * vb4.z; acc[2][7] += p2 * vb4.w;
            acc[3][0] += p3 * va.x;  acc[3][1] += p3 * va.y;
            acc[3][2] += p3 * va.z;  acc[3][3] += p3 * va.w;
            acc[3][4] += p3 * vb4.x; acc[3][5] += p3 * vb4.y;
            acc[3][6] += p3 * vb4.z; acc[3][7] += p3 * vb4.w;
        }
        __syncthreads();  // Ss/Vs reuse + l_sh visibility
    }
    // ---- normalize, write partial output ----
#pragma unroll
    for (int i = 0; i < 4; ++i) {
        int q = ty * 4 + i;
        float inv = 1.f / l_sh[q];
        float* dst = part + ((size_t)g * SEQ + i0 + q) * 1024 + h * 128;
        float4 o1 = {acc[i][0] * inv, acc[i][1] * inv, acc[i][2] * inv, acc[i][3] * inv};
        float4 o2 = {acc[i][4] * inv, acc[i][5] * inv, acc[i][6] * inv, acc[i][7] * inv};
        *(float4*)&dst[tx * 4] = o1;
        *(float4*)&dst[64 + tx * 4] = o2;
    }
}

// attn[s][c] = sum_g part[g][s][c]  (float4 over 2048*1024)
__global__ void sum4_kernel(const float* __restrict__ part, float* __restrict__ attn) {
    int idx = blockIdx.x * 256 + threadIdx.x;  // over float4s: 2048*1024/4 = 524288
    const float4* p = (const float4*)part;
    float4 a = p[idx];
    float4 b = p[idx + 524288];
    float4 c = p[idx + 2 * 524288];
    float4 d = p[idx + 3 * 524288];
    float4 o = {a.x + b.x + c.x + d.x, a.y + b.y + c.y + d.y,
                a.z + b.z + c.z + d.z, a.w + b.w + c.w + d.w};
    ((float4*)attn)[idx] = o;
}

extern "C" void kernel_launch(void* const* d_in, const int* in_sizes, int n_in,
                              void* d_out, int out_size, void* d_ws, size_t ws_size,
                              hipStream_t stream) {
    const float* x  = (const float*)d_in[0];
    const float* Wq = (const float*)d_in[1];
    const float* bq = (const float*)d_in[2];
    const float* Wk = (const float*)d_in[3];
    const float* bk = (const float*)d_in[4];
    const float* Wv = (const float*)d_in[5];
    const float* bv = (const float*)d_in[6];
    const float* Wo = (const float*)d_in[7];
    const float* bo = (const float*)d_in[8];
    const float* W1 = (const float*)d_in[9];
    const float* b1 = (const float*)d_in[10];
    const float* W2 = (const float*)d_in[11];
    const float* b2 = (const float*)d_in[12];
    float* out = (float*)d_out;

    float* q_ws    = (float*)d_ws;                       // 2048*1024
    float* k_ws    = q_ws + (size_t)SEQ * 1024;          // 2048*512
    float* v_ws    = k_ws + (size_t)SEQ * 512;           // 2048*512
    float* attn_ws = v_ws + (size_t)SEQ * 512;           // 2048*1024
    float* o_ws    = attn_ws + (size_t)SEQ * 1024;       // 2048*1024
    float* h1_ws   = o_ws + (size_t)SEQ * 1024;          // 2048*4096
    float* part_ws = h1_ws;  // alias: 4*2048*1024 floats, dead before W1 gemm writes h1

    dim3 blk(16, 16);
    // q/k/v projections
    gemm_kernel<false><<<dim3(1024 / 64, SEQ / 64), blk, 0, stream>>>(
        x, Wq, bq, q_ws, SEQ, 1024, 1024);
    gemm_kernel<false><<<dim3(512 / 64, SEQ / 64), blk, 0, stream>>>(
        x, Wk, bk, k_ws, SEQ, 512, 1024);
    gemm_kernel<false><<<dim3(512 / 64, SEQ / 64), blk, 0, stream>>>(
        x, Wv, bv, v_ws, SEQ, 512, 1024);
    // RoPE in place on q,k
    rope_kernel<<<SEQ, 256, 0, stream>>>(q_ws, k_ws);
    // flash attention per (qtile, head, group) + sum over groups
    flash_attn_kernel<<<dim3(SEQ / TQ, 8, 4), blk, 0, stream>>>(q_ws, k_ws, v_ws, part_ws);
    sum4_kernel<<<2048, 256, 0, stream>>>(part_ws, attn_ws);
    // output projection
    gemm_kernel<false><<<dim3(1024 / 64, SEQ / 64), blk, 0, stream>>>(
        attn_ws, Wo, bo, o_ws, SEQ, 1024, 1024);
    // MLP
    gemm_kernel<true><<<dim3(4096 / 64, SEQ / 64), blk, 0, stream>>>(
        o_ws, W1, b1, h1_ws, SEQ, 4096, 1024);
    gemm_kernel<false><<<dim3(4096 / 64, SEQ / 64), blk, 0, stream>>>(
        h1_ws, W2, b2, out, SEQ, 4096, 4096);
}

// Round 4
// 2058.811 us; speedup vs baseline: 6.5701x; 1.7980x over previous
//
#include <hip/hip_runtime.h>
#include <hip/hip_bf16.h>

#define SEQ 2048

typedef unsigned short ushort_t;
typedef __attribute__((ext_vector_type(8))) short short8;
typedef __attribute__((ext_vector_type(4))) float f32x4;

__device__ __forceinline__ ushort_t f2bf(float f) {
    __hip_bfloat16 h = __float2bfloat16(f);
    return *reinterpret_cast<ushort_t*>(&h);
}

// C[M,N] = A[M,K] @ W[N,K]^T + bias[N], optional SiLU. fp32 accumulate.
// 64x64 tile, 256 threads (16x16), 4x4 micro-tile, BK=16, transposed LDS.
template <bool SILU>
__global__ void gemm_kernel(const float* __restrict__ A, const float* __restrict__ W,
                            const float* __restrict__ bias, float* __restrict__ C,
                            int M, int N, int Kd) {
    __shared__ __align__(16) float As[16][72];
    __shared__ __align__(16) float Ws[16][72];
    const int tx = threadIdx.x, ty = threadIdx.y;
    const int tid = ty * 16 + tx;
    const int m0 = blockIdx.y * 64, n0 = blockIdx.x * 64;
    float acc[4][4] = {};
    for (int k0 = 0; k0 < Kd; k0 += 16) {
#pragma unroll
        for (int it = 0; it < 4; ++it) {
            int idx = tid + it * 256;
            int mm = idx >> 4, kk = idx & 15;
            As[kk][mm] = A[(size_t)(m0 + mm) * Kd + k0 + kk];
            Ws[kk][mm] = W[(size_t)(n0 + mm) * Kd + k0 + kk];
        }
        __syncthreads();
#pragma unroll
        for (int kk = 0; kk < 16; ++kk) {
            float4 a4 = *(const float4*)&As[kk][ty * 4];
            float4 b4 = *(const float4*)&Ws[kk][tx * 4];
            float av[4] = {a4.x, a4.y, a4.z, a4.w};
            float bv[4] = {b4.x, b4.y, b4.z, b4.w};
#pragma unroll
            for (int i = 0; i < 4; ++i)
#pragma unroll
                for (int j = 0; j < 4; ++j)
                    acc[i][j] += av[i] * bv[j];
        }
        __syncthreads();
    }
#pragma unroll
    for (int i = 0; i < 4; ++i) {
        int m = m0 + ty * 4 + i;
#pragma unroll
        for (int j = 0; j < 4; ++j) {
            int n = n0 + tx * 4 + j;
            float v = acc[i][j] + bias[n];
            if (SILU) v = v / (1.f + __expf(-v));
            C[(size_t)m * N + n] = v;
        }
    }
}

// RoPE: read fp32 q (S x 1024, 8 heads) / k (S x 512, 4 heads), write rotated bf16.
__global__ void rope_bf_kernel(const float* __restrict__ qf, const float* __restrict__ kf,
                               ushort_t* __restrict__ qb, ushort_t* __restrict__ kb) {
    const int s = blockIdx.x;
    const float t = (float)s;
    for (int p = threadIdx.x; p < 768; p += 256) {
        int idx = p & 63;
        float invf = powf(10000.f, -(float)(2 * idx) / 128.f);
        float ang = t * invf;
        float c = cosf(ang), sn = sinf(ang);
        if (p < 512) {
            int h = p >> 6;
            const float* src = qf + (size_t)s * 1024 + h * 128 + idx;
            ushort_t* dst = qb + (size_t)s * 1024 + h * 128 + idx;
            float x1 = src[0], x2 = src[64];
            dst[0] = f2bf(x1 * c - x2 * sn);
            dst[64] = f2bf(x2 * c + x1 * sn);
        } else {
            int h = (p - 512) >> 6;
            const float* src = kf + (size_t)s * 512 + h * 128 + idx;
            ushort_t* dst = kb + (size_t)s * 512 + h * 128 + idx;
            float x1 = src[0], x2 = src[64];
            dst[0] = f2bf(x1 * c - x2 * sn);
            dst[64] = f2bf(x2 * c + x1 * sn);
        }
    }
}

__global__ void cvt_bf_kernel(const float* __restrict__ src, ushort_t* __restrict__ dst, int n) {
    int i = blockIdx.x * 256 + threadIdx.x;
    if (i < n) dst[i] = f2bf(src[i]);
}

// MFMA flash attention. Block = (qtile 64, head h, group g), 256 threads = 4 waves.
// Wave w owns q rows [w*16, w*16+16). Online softmax state in registers.
// Layouts (HW-verified, learn_hip m89/m91/m120):
//   A-frag: A[m=lane&15][k=quad*8+j], B-frag same on [n][k] data, C/D: col=lane&15,row=quad*4+reg.
__global__ __launch_bounds__(256) void mfma_attn_kernel(
    const ushort_t* __restrict__ qb, const ushort_t* __restrict__ kb,
    const ushort_t* __restrict__ vb, float* __restrict__ part) {
    const int qt = 31 - blockIdx.x;  // heavy tiles first
    const int i0 = qt * 64;
    const int h = blockIdx.y;
    const int g = blockIdx.z;
    const int tid = threadIdx.x;
    const int w = tid >> 6;
    const int lane = tid & 63;
    const int l15 = lane & 15;
    const int quad = lane >> 4;

    __shared__ __align__(16) ushort_t P_lds[4][16][72];  // per-wave P, stride 72 (16B rows)
    __shared__ __align__(16) ushort_t Vt[128][72];       // V transposed [d][j]

    // Q A-frags: this wave's 16 rows, K=128 in 4 chunks of 32
    short8 aq[4];
    {
        const ushort_t* qrow = qb + (size_t)(i0 + w * 16 + l15) * 1024 + h * 128 + quad * 8;
#pragma unroll
        for (int kc = 0; kc < 4; ++kc) aq[kc] = *(const short8*)(qrow + kc * 32);
    }

    f32x4 oacc[8];
#pragma unroll
    for (int nt = 0; nt < 8; ++nt) oacc[nt] = (f32x4){0.f, 0.f, 0.f, 0.f};
    float m_st[4] = {-1e30f, -1e30f, -1e30f, -1e30f};
    float l_st[4] = {0.f, 0.f, 0.f, 0.f};

    for (int jt = 0; jt <= qt; ++jt) {
        const int j0 = jt * 64;
        // ---- S = Q K^T : 4 col-tiles x 4 k-chunks ----
        f32x4 sacc[4];
#pragma unroll
        for (int nt = 0; nt < 4; ++nt) sacc[nt] = (f32x4){0.f, 0.f, 0.f, 0.f};
#pragma unroll
        for (int nt = 0; nt < 4; ++nt) {
            const ushort_t* krow = kb + (size_t)(j0 + nt * 16 + l15) * 512 + g * 128 + quad * 8;
#pragma unroll
            for (int kc = 0; kc < 4; ++kc) {
                short8 bk = *(const short8*)(krow + kc * 32);
                sacc[nt] = __builtin_amdgcn_mfma_f32_16x16x32_bf16(aq[kc], bk, sacc[nt], 0, 0, 0);
            }
        }
        // ---- scale + causal mask (diagonal tile only) ----
#pragma unroll
        for (int nt = 0; nt < 4; ++nt)
#pragma unroll
            for (int r = 0; r < 4; ++r) sacc[nt][r] *= 0.08838834764831845f;
        if (jt == qt) {
#pragma unroll
            for (int nt = 0; nt < 4; ++nt) {
                int colg = nt * 16 + l15;
#pragma unroll
                for (int r = 0; r < 4; ++r) {
                    int rowg = w * 16 + quad * 4 + r;
                    if (colg > rowg) sacc[nt][r] = -1e30f;
                }
            }
        }
        // ---- online softmax (registers + 16-lane shuffles) ----
        float alpha[4];
#pragma unroll
        for (int r = 0; r < 4; ++r) {
            float mx = fmaxf(fmaxf(sacc[0][r], sacc[1][r]), fmaxf(sacc[2][r], sacc[3][r]));
            mx = fmaxf(mx, __shfl_xor(mx, 1));
            mx = fmaxf(mx, __shfl_xor(mx, 2));
            mx = fmaxf(mx, __shfl_xor(mx, 4));
            mx = fmaxf(mx, __shfl_xor(mx, 8));
            float mn = fmaxf(m_st[r], mx);
            alpha[r] = __expf(m_st[r] - mn);
            m_st[r] = mn;
        }
        float lsum[4] = {0.f, 0.f, 0.f, 0.f};
#pragma unroll
        for (int nt = 0; nt < 4; ++nt)
#pragma unroll
            for (int r = 0; r < 4; ++r) {
                float e = __expf(sacc[nt][r] - m_st[r]);
                sacc[nt][r] = e;
                lsum[r] += e;
            }
#pragma unroll
        for (int r = 0; r < 4; ++r) {
            float s = lsum[r];
            s += __shfl_xor(s, 1);
            s += __shfl_xor(s, 2);
            s += __shfl_xor(s, 4);
            s += __shfl_xor(s, 8);
            l_st[r] = l_st[r] * alpha[r] + s;
        }
        // ---- P -> per-wave LDS (bf16), rescale O ----
#pragma unroll
        for (int nt = 0; nt < 4; ++nt)
#pragma unroll
            for (int r = 0; r < 4; ++r)
                P_lds[w][quad * 4 + r][nt * 16 + l15] = f2bf(sacc[nt][r]);
#pragma unroll
        for (int nt = 0; nt < 8; ++nt)
#pragma unroll
            for (int r = 0; r < 4; ++r) oacc[nt][r] *= alpha[r];
        __syncthreads();  // prior tile's Vt reads complete
        // ---- stage V^T [d][j] ----
#pragma unroll
        for (int it = 0; it < 4; ++it) {
            int u = tid + it * 256;       // 1024 units = 64 j x 16 col-groups
            int j = u & 63, cg = u >> 6;
            short8 vv = *(const short8*)(vb + (size_t)(j0 + j) * 512 + g * 128 + cg * 8);
            const ushort_t* vp = (const ushort_t*)&vv;
#pragma unroll
            for (int i = 0; i < 8; ++i) Vt[cg * 8 + i][j] = vp[i];
        }
        __syncthreads();
        // ---- O += P V : 8 d-tiles x 2 k-chunks ----
#pragma unroll
        for (int c = 0; c < 2; ++c) {
            short8 ap = *(const short8*)&P_lds[w][l15][c * 32 + quad * 8];
#pragma unroll
            for (int nt = 0; nt < 8; ++nt) {
                short8 bv = *(const short8*)&Vt[nt * 16 + l15][c * 32 + quad * 8];
                oacc[nt] = __builtin_amdgcn_mfma_f32_16x16x32_bf16(ap, bv, oacc[nt], 0, 0, 0);
            }
        }
    }
    // ---- normalize, write per-group partial ----
#pragma unroll
    for (int r = 0; r < 4; ++r) {
        float inv = 1.f / l_st[r];
        int row = i0 + w * 16 + quad * 4 + r;
        float* dst = part + ((size_t)g * SEQ + row) * 1024 + h * 128;
#pragma unroll
        for (int nt = 0; nt < 8; ++nt) dst[nt * 16 + l15] = oacc[nt][r] * inv;
    }
}

// attn[s][c] = sum_g part[g][s][c]  (float4 over 2048*1024)
__global__ void sum4_kernel(const float* __restrict__ part, float* __restrict__ attn) {
    int idx = blockIdx.x * 256 + threadIdx.x;
    const float4* p = (const float4*)part;
    float4 a = p[idx];
    float4 b = p[idx + 524288];
    float4 c = p[idx + 2 * 524288];
    float4 d = p[idx + 3 * 524288];
    float4 o = {a.x + b.x + c.x + d.x, a.y + b.y + c.y + d.y,
                a.z + b.z + c.z + d.z, a.w + b.w + c.w + d.w};
    ((float4*)attn)[idx] = o;
}

extern "C" void kernel_launch(void* const* d_in, const int* in_sizes, int n_in,
                              void* d_out, int out_size, void* d_ws, size_t ws_size,
                              hipStream_t stream) {
    const float* x  = (const float*)d_in[0];
    const float* Wq = (const float*)d_in[1];
    const float* bq = (const float*)d_in[2];
    const float* Wk = (const float*)d_in[3];
    const float* bk = (const float*)d_in[4];
    const float* Wv = (const float*)d_in[5];
    const float* bv = (const float*)d_in[6];
    const float* Wo = (const float*)d_in[7];
    const float* bo = (const float*)d_in[8];
    const float* W1 = (const float*)d_in[9];
    const float* b1 = (const float*)d_in[10];
    const float* W2 = (const float*)d_in[11];
    const float* b2 = (const float*)d_in[12];
    float* out = (float*)d_out;

    float* q_ws    = (float*)d_ws;                       // 2048*1024 f32
    float* k_ws    = q_ws + (size_t)SEQ * 1024;          // 2048*512  f32
    float* v_ws    = k_ws + (size_t)SEQ * 512;           // 2048*512  f32
    float* attn_ws = v_ws + (size_t)SEQ * 512;           // 2048*1024 f32
    float* o_ws    = attn_ws + (size_t)SEQ * 1024;       // 2048*1024 f32
    float* h1_ws   = o_ws + (size_t)SEQ * 1024;          // 2048*4096 f32
    float* part_ws = h1_ws;                              // alias: dead before W1 gemm
    // bf16 q/k/v alias o_ws (8 MB): dead before Wo gemm writes o_ws
    ushort_t* q_bf = (ushort_t*)o_ws;                    // 2048*1024 bf16 (4 MB)
    ushort_t* k_bf = q_bf + (size_t)SEQ * 1024;          // 2048*512 bf16 (2 MB)
    ushort_t* v_bf = k_bf + (size_t)SEQ * 512;           // 2048*512 bf16 (2 MB)

    dim3 blk(16, 16);
    // q/k/v projections (fp32)
    gemm_kernel<false><<<dim3(1024 / 64, SEQ / 64), blk, 0, stream>>>(
        x, Wq, bq, q_ws, SEQ, 1024, 1024);
    gemm_kernel<false><<<dim3(512 / 64, SEQ / 64), blk, 0, stream>>>(
        x, Wk, bk, k_ws, SEQ, 512, 1024);
    gemm_kernel<false><<<dim3(512 / 64, SEQ / 64), blk, 0, stream>>>(
        x, Wv, bv, v_ws, SEQ, 512, 1024);
    // RoPE -> bf16 q,k ; convert v -> bf16
    rope_bf_kernel<<<SEQ, 256, 0, stream>>>(q_ws, k_ws, q_bf, k_bf);
    cvt_bf_kernel<<<(SEQ * 512) / 256, 256, 0, stream>>>(v_ws, v_bf, SEQ * 512);
    // MFMA flash attention per (qtile, head, group) + sum over groups
    mfma_attn_kernel<<<dim3(SEQ / 64, 8, 4), 256, 0, stream>>>(q_bf, k_bf, v_bf, part_ws);
    sum4_kernel<<<2048, 256, 0, stream>>>(part_ws, attn_ws);
    // output projection
    gemm_kernel<false><<<dim3(1024 / 64, SEQ / 64), blk, 0, stream>>>(
        attn_ws, Wo, bo, o_ws, SEQ, 1024, 1024);
    // MLP
    gemm_kernel<true><<<dim3(4096 / 64, SEQ / 64), blk, 0, stream>>>(
        o_ws, W1, b1, h1_ws, SEQ, 4096, 1024);
    gemm_kernel<false><<<dim3(4096 / 64, SEQ / 64), blk, 0, stream>>>(
        h1_ws, W2, b2, out, SEQ, 4096, 4096);
}

// Round 5
// 849.456 us; speedup vs baseline: 15.9239x; 2.4237x over previous
//
#include <hip/hip_runtime.h>
#include <hip/hip_bf16.h>

#define SEQ 2048

typedef unsigned short ushort_t;
typedef __attribute__((ext_vector_type(8))) short short8;
typedef __attribute__((ext_vector_type(4))) float f32x4;

__device__ __forceinline__ ushort_t f2bf(float f) {
    __hip_bfloat16 h = __float2bfloat16(f);
    return *reinterpret_cast<ushort_t*>(&h);
}

__device__ __forceinline__ void st(float* p, float v) { *p = v; }
__device__ __forceinline__ void st(ushort_t* p, float v) { *p = f2bf(v); }

// ---- staging helpers: global -> LDS bf16 [128][32] tile ----
__device__ __forceinline__ void stage_tile(ushort_t* dst, const float* src, int ld,
                                           int row0, int k0, int tid) {
#pragma unroll
    for (int c = 0; c < 4; ++c) {
        int flat = c * 256 + tid;          // 1024 float4 units
        int row = flat >> 3, col4 = flat & 7;
        float4 a = *(const float4*)&src[(size_t)(row0 + row) * ld + k0 + col4 * 4];
        union { ushort_t u[4]; unsigned long long ll; } pk;
        pk.u[0] = f2bf(a.x); pk.u[1] = f2bf(a.y);
        pk.u[2] = f2bf(a.z); pk.u[3] = f2bf(a.w);
        *(unsigned long long*)&dst[row * 32 + col4 * 4] = pk.ll;
    }
}
__device__ __forceinline__ void stage_tile(ushort_t* dst, const ushort_t* src, int ld,
                                           int row0, int k0, int tid) {
#pragma unroll
    for (int c = 0; c < 2; ++c) {
        int flat = c * 256 + tid;          // 512 short8 units
        int row = flat >> 2, col8 = flat & 3;
        *(short8*)&dst[row * 32 + col8 * 8] =
            *(const short8*)&src[(size_t)(row0 + row) * ld + k0 + col8 * 8];
    }
}

// C[M,N] = A[M,K] @ W[N,K]^T + bias[N]. bf16 MFMA, fp32 accumulate.
// 128x128 tile, 256 threads = 4 waves (2x2 of 64x64), BK=32.
// Frag layouts HW-verified (learn_hip m89/m91): A[m=l15][k=quad*8+j]; C/D col=l15,row=quad*4+r.
template <typename TA, bool SILU, typename TC>
__global__ __launch_bounds__(256) void mfma_gemm_kernel(
    const TA* __restrict__ A, const float* __restrict__ W,
    const float* __restrict__ bias, TC* __restrict__ C, int M, int N, int Kd) {
    __shared__ __align__(16) ushort_t As[128 * 32];
    __shared__ __align__(16) ushort_t Bs[128 * 32];
    const int tid = threadIdx.x;
    const int w = tid >> 6, lane = tid & 63, l15 = lane & 15, quad = lane >> 4;
    const int m0 = blockIdx.y * 128, n0 = blockIdx.x * 128;
    const int rw = (w >> 1) * 64, cw = (w & 1) * 64;
    f32x4 acc[4][4];
#pragma unroll
    for (int mt = 0; mt < 4; ++mt)
#pragma unroll
        for (int nt = 0; nt < 4; ++nt) acc[mt][nt] = (f32x4){0.f, 0.f, 0.f, 0.f};

    for (int k0 = 0; k0 < Kd; k0 += 32) {
        stage_tile(As, A, Kd, m0, k0, tid);
        stage_tile(Bs, W, Kd, n0, k0, tid);
        __syncthreads();
        short8 af[4], bfr[4];
#pragma unroll
        for (int mt = 0; mt < 4; ++mt)
            af[mt] = *(const short8*)&As[(rw + mt * 16 + l15) * 32 + quad * 8];
#pragma unroll
        for (int nt = 0; nt < 4; ++nt)
            bfr[nt] = *(const short8*)&Bs[(cw + nt * 16 + l15) * 32 + quad * 8];
#pragma unroll
        for (int mt = 0; mt < 4; ++mt)
#pragma unroll
            for (int nt = 0; nt < 4; ++nt)
                acc[mt][nt] = __builtin_amdgcn_mfma_f32_16x16x32_bf16(
                    af[mt], bfr[nt], acc[mt][nt], 0, 0, 0);
        __syncthreads();
    }
#pragma unroll
    for (int nt = 0; nt < 4; ++nt) {
        int col = n0 + cw + nt * 16 + l15;
        float bb = bias[col];
#pragma unroll
        for (int mt = 0; mt < 4; ++mt)
#pragma unroll
            for (int r = 0; r < 4; ++r) {
                int row = m0 + rw + mt * 16 + quad * 4 + r;
                float v = acc[mt][nt][r] + bb;
                if (SILU) v = v / (1.f + __expf(-v));
                st(&C[(size_t)row * N + col], v);
            }
    }
}

// RoPE: read fp32 q (S x 1024, 8 heads) / k (S x 512, 4 heads), write rotated bf16.
__global__ void rope_bf_kernel(const float* __restrict__ qf, const float* __restrict__ kf,
                               ushort_t* __restrict__ qb, ushort_t* __restrict__ kb) {
    const int s = blockIdx.x;
    const float t = (float)s;
    for (int p = threadIdx.x; p < 768; p += 256) {
        int idx = p & 63;
        float invf = powf(10000.f, -(float)(2 * idx) / 128.f);
        float ang = t * invf;
        float c = cosf(ang), sn = sinf(ang);
        if (p < 512) {
            int h = p >> 6;
            const float* src = qf + (size_t)s * 1024 + h * 128 + idx;
            ushort_t* dst = qb + (size_t)s * 1024 + h * 128 + idx;
            float x1 = src[0], x2 = src[64];
            dst[0] = f2bf(x1 * c - x2 * sn);
            dst[64] = f2bf(x2 * c + x1 * sn);
        } else {
            int h = (p - 512) >> 6;
            const float* src = kf + (size_t)s * 512 + h * 128 + idx;
            ushort_t* dst = kb + (size_t)s * 512 + h * 128 + idx;
            float x1 = src[0], x2 = src[64];
            dst[0] = f2bf(x1 * c - x2 * sn);
            dst[64] = f2bf(x2 * c + x1 * sn);
        }
    }
}

// MFMA flash attention (unchanged from round 4, verified).
__global__ __launch_bounds__(256) void mfma_attn_kernel(
    const ushort_t* __restrict__ qb, const ushort_t* __restrict__ kb,
    const ushort_t* __restrict__ vb, float* __restrict__ part) {
    const int qt = 31 - blockIdx.x;  // heavy tiles first
    const int i0 = qt * 64;
    const int h = blockIdx.y;
    const int g = blockIdx.z;
    const int tid = threadIdx.x;
    const int w = tid >> 6;
    const int lane = tid & 63;
    const int l15 = lane & 15;
    const int quad = lane >> 4;

    __shared__ __align__(16) ushort_t P_lds[4][16][72];
    __shared__ __align__(16) ushort_t Vt[128][72];

    short8 aq[4];
    {
        const ushort_t* qrow = qb + (size_t)(i0 + w * 16 + l15) * 1024 + h * 128 + quad * 8;
#pragma unroll
        for (int kc = 0; kc < 4; ++kc) aq[kc] = *(const short8*)(qrow + kc * 32);
    }

    f32x4 oacc[8];
#pragma unroll
    for (int nt = 0; nt < 8; ++nt) oacc[nt] = (f32x4){0.f, 0.f, 0.f, 0.f};
    float m_st[4] = {-1e30f, -1e30f, -1e30f, -1e30f};
    float l_st[4] = {0.f, 0.f, 0.f, 0.f};

    for (int jt = 0; jt <= qt; ++jt) {
        const int j0 = jt * 64;
        f32x4 sacc[4];
#pragma unroll
        for (int nt = 0; nt < 4; ++nt) sacc[nt] = (f32x4){0.f, 0.f, 0.f, 0.f};
#pragma unroll
        for (int nt = 0; nt < 4; ++nt) {
            const ushort_t* krow = kb + (size_t)(j0 + nt * 16 + l15) * 512 + g * 128 + quad * 8;
#pragma unroll
            for (int kc = 0; kc < 4; ++kc) {
                short8 bk = *(const short8*)(krow + kc * 32);
                sacc[nt] = __builtin_amdgcn_mfma_f32_16x16x32_bf16(aq[kc], bk, sacc[nt], 0, 0, 0);
            }
        }
#pragma unroll
        for (int nt = 0; nt < 4; ++nt)
#pragma unroll
            for (int r = 0; r < 4; ++r) sacc[nt][r] *= 0.08838834764831845f;
        if (jt == qt) {
#pragma unroll
            for (int nt = 0; nt < 4; ++nt) {
                int colg = nt * 16 + l15;
#pragma unroll
                for (int r = 0; r < 4; ++r) {
                    int rowg = w * 16 + quad * 4 + r;
                    if (colg > rowg) sacc[nt][r] = -1e30f;
                }
            }
        }
        float alpha[4];
#pragma unroll
        for (int r = 0; r < 4; ++r) {
            float mx = fmaxf(fmaxf(sacc[0][r], sacc[1][r]), fmaxf(sacc[2][r], sacc[3][r]));
            mx = fmaxf(mx, __shfl_xor(mx, 1));
            mx = fmaxf(mx, __shfl_xor(mx, 2));
            mx = fmaxf(mx, __shfl_xor(mx, 4));
            mx = fmaxf(mx, __shfl_xor(mx, 8));
            float mn = fmaxf(m_st[r], mx);
            alpha[r] = __expf(m_st[r] - mn);
            m_st[r] = mn;
        }
        float lsum[4] = {0.f, 0.f, 0.f, 0.f};
#pragma unroll
        for (int nt = 0; nt < 4; ++nt)
#pragma unroll
            for (int r = 0; r < 4; ++r) {
                float e = __expf(sacc[nt][r] - m_st[r]);
                sacc[nt][r] = e;
                lsum[r] += e;
            }
#pragma unroll
        for (int r = 0; r < 4; ++r) {
            float s = lsum[r];
            s += __shfl_xor(s, 1);
            s += __shfl_xor(s, 2);
            s += __shfl_xor(s, 4);
            s += __shfl_xor(s, 8);
            l_st[r] = l_st[r] * alpha[r] + s;
        }
#pragma unroll
        for (int nt = 0; nt < 4; ++nt)
#pragma unroll
            for (int r = 0; r < 4; ++r)
                P_lds[w][quad * 4 + r][nt * 16 + l15] = f2bf(sacc[nt][r]);
#pragma unroll
        for (int nt = 0; nt < 8; ++nt)
#pragma unroll
            for (int r = 0; r < 4; ++r) oacc[nt][r] *= alpha[r];
        __syncthreads();
#pragma unroll
        for (int it = 0; it < 4; ++it) {
            int u = tid + it * 256;
            int j = u & 63, cg = u >> 6;
            short8 vv = *(const short8*)(vb + (size_t)(j0 + j) * 512 + g * 128 + cg * 8);
            const ushort_t* vp = (const ushort_t*)&vv;
#pragma unroll
            for (int i = 0; i < 8; ++i) Vt[cg * 8 + i][j] = vp[i];
        }
        __syncthreads();
#pragma unroll
        for (int c = 0; c < 2; ++c) {
            short8 ap = *(const short8*)&P_lds[w][l15][c * 32 + quad * 8];
#pragma unroll
            for (int nt = 0; nt < 8; ++nt) {
                short8 bv = *(const short8*)&Vt[nt * 16 + l15][c * 32 + quad * 8];
                oacc[nt] = __builtin_amdgcn_mfma_f32_16x16x32_bf16(ap, bv, oacc[nt], 0, 0, 0);
            }
        }
    }
#pragma unroll
    for (int r = 0; r < 4; ++r) {
        float inv = 1.f / l_st[r];
        int row = i0 + w * 16 + quad * 4 + r;
        float* dst = part + ((size_t)g * SEQ + row) * 1024 + h * 128;
#pragma unroll
        for (int nt = 0; nt < 8; ++nt) dst[nt * 16 + l15] = oacc[nt][r] * inv;
    }
}

// attn_bf[s][c] = bf16( sum_g part[g][s][c] )
__global__ void sum4_bf_kernel(const float* __restrict__ part, ushort_t* __restrict__ attn) {
    int idx = blockIdx.x * 256 + threadIdx.x;  // 524288 float4 units
    const float4* p = (const float4*)part;
    float4 a = p[idx];
    float4 b = p[idx + 524288];
    float4 c = p[idx + 2 * 524288];
    float4 d = p[idx + 3 * 524288];
    union { ushort_t u[4]; unsigned long long ll; } pk;
    pk.u[0] = f2bf(a.x + b.x + c.x + d.x);
    pk.u[1] = f2bf(a.y + b.y + c.y + d.y);
    pk.u[2] = f2bf(a.z + b.z + c.z + d.z);
    pk.u[3] = f2bf(a.w + b.w + c.w + d.w);
    *(unsigned long long*)&attn[(size_t)idx * 4] = pk.ll;
}

extern "C" void kernel_launch(void* const* d_in, const int* in_sizes, int n_in,
                              void* d_out, int out_size, void* d_ws, size_t ws_size,
                              hipStream_t stream) {
    const float* x  = (const float*)d_in[0];
    const float* Wq = (const float*)d_in[1];
    const float* bq = (const float*)d_in[2];
    const float* Wk = (const float*)d_in[3];
    const float* bk = (const float*)d_in[4];
    const float* Wv = (const float*)d_in[5];
    const float* bv = (const float*)d_in[6];
    const float* Wo = (const float*)d_in[7];
    const float* bo = (const float*)d_in[8];
    const float* W1 = (const float*)d_in[9];
    const float* b1 = (const float*)d_in[10];
    const float* W2 = (const float*)d_in[11];
    const float* b2 = (const float*)d_in[12];
    float* out = (float*)d_out;

    // Workspace layout (MB offsets), 52 MB total:
    //  0-8   q_f32  (dead after rope)  -> 0-4 attn_bf, 4-8 o_bf
    //  8-12  k_f32  (dead after rope)
    // 12-14  v_bf
    // 14-18  q_bf
    // 18-20  k_bf
    // 20-52  part f32 (dead after sum4) -> 20-36 h1_bf
    char* ws = (char*)d_ws;
    float*    q_f32   = (float*)(ws);
    float*    k_f32   = (float*)(ws + ((size_t)8 << 20));
    ushort_t* v_bf    = (ushort_t*)(ws + ((size_t)12 << 20));
    ushort_t* q_bf    = (ushort_t*)(ws + ((size_t)14 << 20));
    ushort_t* k_bf    = (ushort_t*)(ws + ((size_t)18 << 20));
    float*    part    = (float*)(ws + ((size_t)20 << 20));
    ushort_t* attn_bf = (ushort_t*)(ws);
    ushort_t* o_bf    = (ushort_t*)(ws + ((size_t)4 << 20));
    ushort_t* h1_bf   = (ushort_t*)(ws + ((size_t)20 << 20));

    // q/k/v projections (fp32 in, bf16 MFMA, fp32/bf16 out)
    mfma_gemm_kernel<float, false, float><<<dim3(8, 16), 256, 0, stream>>>(
        x, Wq, bq, q_f32, SEQ, 1024, 1024);
    mfma_gemm_kernel<float, false, float><<<dim3(4, 16), 256, 0, stream>>>(
        x, Wk, bk, k_f32, SEQ, 512, 1024);
    mfma_gemm_kernel<float, false, ushort_t><<<dim3(4, 16), 256, 0, stream>>>(
        x, Wv, bv, v_bf, SEQ, 512, 1024);
    // RoPE -> bf16 q,k
    rope_bf_kernel<<<SEQ, 256, 0, stream>>>(q_f32, k_f32, q_bf, k_bf);
    // flash attention + group sum
    mfma_attn_kernel<<<dim3(32, 8, 4), 256, 0, stream>>>(q_bf, k_bf, v_bf, part);
    sum4_bf_kernel<<<2048, 256, 0, stream>>>(part, attn_bf);
    // output projection -> bf16 o
    mfma_gemm_kernel<ushort_t, false, ushort_t><<<dim3(8, 16), 256, 0, stream>>>(
        attn_bf, Wo, bo, o_bf, SEQ, 1024, 1024);
    // MLP: W1+SiLU -> bf16 h1 ; W2 -> fp32 out
    mfma_gemm_kernel<ushort_t, true, ushort_t><<<dim3(32, 16), 256, 0, stream>>>(
        o_bf, W1, b1, h1_bf, SEQ, 4096, 1024);
    mfma_gemm_kernel<ushort_t, false, float><<<dim3(32, 16), 256, 0, stream>>>(
        h1_bf, W2, b2, out, SEQ, 4096, 4096);
}

// Round 6
// 753.789 us; speedup vs baseline: 17.9449x; 1.1269x over previous
//
#include <hip/hip_runtime.h>
#include <hip/hip_bf16.h>

#define SEQ 2048

typedef unsigned short ushort_t;
typedef __attribute__((ext_vector_type(8))) short short8;
typedef __attribute__((ext_vector_type(4))) float f32x4;

__device__ __forceinline__ ushort_t f2bf(float f) {
    __hip_bfloat16 h = __float2bfloat16(f);
    return *reinterpret_cast<ushort_t*>(&h);
}

__device__ __forceinline__ void st(float* p, float v) { *p = v; }
__device__ __forceinline__ void st(ushort_t* p, float v) { *p = f2bf(v); }

// ---- staging helpers: global -> LDS bf16 [128][32] tile ----
__device__ __forceinline__ void stage_tile(ushort_t* dst, const float* src, int ld,
                                           int row0, int k0, int tid) {
#pragma unroll
    for (int c = 0; c < 4; ++c) {
        int flat = c * 256 + tid;          // 1024 float4 units
        int row = flat >> 3, col4 = flat & 7;
        float4 a = *(const float4*)&src[(size_t)(row0 + row) * ld + k0 + col4 * 4];
        union { ushort_t u[4]; unsigned long long ll; } pk;
        pk.u[0] = f2bf(a.x); pk.u[1] = f2bf(a.y);
        pk.u[2] = f2bf(a.z); pk.u[3] = f2bf(a.w);
        *(unsigned long long*)&dst[row * 32 + col4 * 4] = pk.ll;
    }
}
__device__ __forceinline__ void stage_tile(ushort_t* dst, const ushort_t* src, int ld,
                                           int row0, int k0, int tid) {
#pragma unroll
    for (int c = 0; c < 2; ++c) {
        int flat = c * 256 + tid;          // 512 short8 units
        int row = flat >> 2, col8 = flat & 3;
        *(short8*)&dst[row * 32 + col8 * 8] =
            *(const short8*)&src[(size_t)(row0 + row) * ld + k0 + col8 * 8];
    }
}

// C[M,N] = A[M,K] @ W[N,K]^T + bias[N]. bf16 MFMA, fp32 accumulate.
// 128x128 tile, 256 threads = 4 waves (2x2 of 64x64), BK=32.
template <typename TA, bool SILU, typename TC>
__global__ __launch_bounds__(256) void mfma_gemm_kernel(
    const TA* __restrict__ A, const float* __restrict__ W,
    const float* __restrict__ bias, TC* __restrict__ C, int M, int N, int Kd) {
    __shared__ __align__(16) ushort_t As[128 * 32];
    __shared__ __align__(16) ushort_t Bs[128 * 32];
    const int tid = threadIdx.x;
    const int w = tid >> 6, lane = tid & 63, l15 = lane & 15, quad = lane >> 4;
    const int m0 = blockIdx.y * 128, n0 = blockIdx.x * 128;
    const int rw = (w >> 1) * 64, cw = (w & 1) * 64;
    f32x4 acc[4][4];
#pragma unroll
    for (int mt = 0; mt < 4; ++mt)
#pragma unroll
        for (int nt = 0; nt < 4; ++nt) acc[mt][nt] = (f32x4){0.f, 0.f, 0.f, 0.f};

    for (int k0 = 0; k0 < Kd; k0 += 32) {
        stage_tile(As, A, Kd, m0, k0, tid);
        stage_tile(Bs, W, Kd, n0, k0, tid);
        __syncthreads();
        short8 af[4], bfr[4];
#pragma unroll
        for (int mt = 0; mt < 4; ++mt)
            af[mt] = *(const short8*)&As[(rw + mt * 16 + l15) * 32 + quad * 8];
#pragma unroll
        for (int nt = 0; nt < 4; ++nt)
            bfr[nt] = *(const short8*)&Bs[(cw + nt * 16 + l15) * 32 + quad * 8];
#pragma unroll
        for (int mt = 0; mt < 4; ++mt)
#pragma unroll
            for (int nt = 0; nt < 4; ++nt)
                acc[mt][nt] = __builtin_amdgcn_mfma_f32_16x16x32_bf16(
                    af[mt], bfr[nt], acc[mt][nt], 0, 0, 0);
        __syncthreads();
    }
#pragma unroll
    for (int nt = 0; nt < 4; ++nt) {
        int col = n0 + cw + nt * 16 + l15;
        float bb = bias[col];
#pragma unroll
        for (int mt = 0; mt < 4; ++mt)
#pragma unroll
            for (int r = 0; r < 4; ++r) {
                int row = m0 + rw + mt * 16 + quad * 4 + r;
                float v = acc[mt][nt][r] + bb;
                if (SILU) v = v / (1.f + __expf(-v));
                st(&C[(size_t)row * N + col], v);
            }
    }
}

// RoPE: read fp32 q (S x 1024, 8 heads) / k (S x 512, 4 heads), write rotated bf16.
__global__ void rope_bf_kernel(const float* __restrict__ qf, const float* __restrict__ kf,
                               ushort_t* __restrict__ qb, ushort_t* __restrict__ kb) {
    const int s = blockIdx.x;
    const float t = (float)s;
    for (int p = threadIdx.x; p < 768; p += 256) {
        int idx = p & 63;
        float invf = powf(10000.f, -(float)(2 * idx) / 128.f);
        float ang = t * invf;
        float c = cosf(ang), sn = sinf(ang);
        if (p < 512) {
            int h = p >> 6;
            const float* src = qf + (size_t)s * 1024 + h * 128 + idx;
            ushort_t* dst = qb + (size_t)s * 1024 + h * 128 + idx;
            float x1 = src[0], x2 = src[64];
            dst[0] = f2bf(x1 * c - x2 * sn);
            dst[64] = f2bf(x2 * c + x1 * sn);
        } else {
            int h = (p - 512) >> 6;
            const float* src = kf + (size_t)s * 512 + h * 128 + idx;
            ushort_t* dst = kb + (size_t)s * 512 + h * 128 + idx;
            float x1 = src[0], x2 = src[64];
            dst[0] = f2bf(x1 * c - x2 * sn);
            dst[64] = f2bf(x2 * c + x1 * sn);
        }
    }
}

// V [2048][512] bf16 -> V^T [512][2048] bf16, 64x64 LDS tiles.
__global__ void transpose_v_kernel(const ushort_t* __restrict__ v, ushort_t* __restrict__ vT) {
    __shared__ __align__(16) ushort_t t[64][72];
    const int s0 = blockIdx.x * 64, d0 = blockIdx.y * 64;
    const int tid = threadIdx.x;
#pragma unroll
    for (int it = 0; it < 2; ++it) {
        int u = tid + it * 256;
        int r = u >> 3, c8 = u & 7;
        *(short8*)&t[r][c8 * 8] = *(const short8*)&v[(size_t)(s0 + r) * 512 + d0 + c8 * 8];
    }
    __syncthreads();
#pragma unroll
    for (int it = 0; it < 2; ++it) {
        int u = tid + it * 256;
        int r = u >> 3, c8 = u & 7;  // r: output d-row, c8: chunk along s
        short8 o;
        ushort_t* op = (ushort_t*)&o;
#pragma unroll
        for (int i = 0; i < 8; ++i) op[i] = t[c8 * 8 + i][r];
        *(short8*)&vT[(size_t)(d0 + r) * 2048 + s0 + c8 * 8] = o;
    }
}

// MFMA flash attention. 1-D grid 1024: hg = lid&31 (h,g), qi = lid>>5,
// qt = (qi*5+hg)&31 -- decorrelates qt from CU under round-robin dispatch.
// 4 waves; wave w owns q rows [w*16, w*16+16). One barrier per j-tile
// (double-buffered Vt). V comes pre-transposed: vT[g][128][2048].
__global__ __launch_bounds__(256) void mfma_attn_kernel(
    const ushort_t* __restrict__ qb, const ushort_t* __restrict__ kb,
    const ushort_t* __restrict__ vT, float* __restrict__ part) {
    const int lid = blockIdx.x;
    const int hg = lid & 31;
    const int h = hg >> 2, g = hg & 3;
    const int qi = lid >> 5;
    const int qt = (qi * 5 + hg) & 31;
    const int i0 = qt * 64;
    const int tid = threadIdx.x;
    const int w = tid >> 6;
    const int lane = tid & 63;
    const int l15 = lane & 15;
    const int quad = lane >> 4;

    __shared__ __align__(16) ushort_t P_lds[4][16][72];
    __shared__ __align__(16) ushort_t Vt[2][128][72];

    const ushort_t* vtg = vT + (size_t)g * 128 * 2048;

    short8 aq[4];
    {
        const ushort_t* qrow = qb + (size_t)(i0 + w * 16 + l15) * 1024 + h * 128 + quad * 8;
#pragma unroll
        for (int kc = 0; kc < 4; ++kc) aq[kc] = *(const short8*)(qrow + kc * 32);
    }

    f32x4 oacc[8];
#pragma unroll
    for (int nt = 0; nt < 8; ++nt) oacc[nt] = (f32x4){0.f, 0.f, 0.f, 0.f};
    float m_st[4] = {-1e30f, -1e30f, -1e30f, -1e30f};
    float l_st[4] = {0.f, 0.f, 0.f, 0.f};

    for (int jt = 0; jt <= qt; ++jt) {
        const int j0 = jt * 64;
        const int buf = jt & 1;
        // ---- prefetch V^T tile into registers (independent of softmax) ----
        short8 vreg[4];
#pragma unroll
        for (int it = 0; it < 4; ++it) {
            int u = tid + it * 256;
            int d = u >> 3, c8 = u & 7;
            vreg[it] = *(const short8*)&vtg[(size_t)d * 2048 + j0 + c8 * 8];
        }
        // ---- S = Q K^T ----
        f32x4 sacc[4];
#pragma unroll
        for (int nt = 0; nt < 4; ++nt) sacc[nt] = (f32x4){0.f, 0.f, 0.f, 0.f};
#pragma unroll
        for (int nt = 0; nt < 4; ++nt) {
            const ushort_t* krow = kb + (size_t)(j0 + nt * 16 + l15) * 512 + g * 128 + quad * 8;
#pragma unroll
            for (int kc = 0; kc < 4; ++kc) {
                short8 bk = *(const short8*)(krow + kc * 32);
                sacc[nt] = __builtin_amdgcn_mfma_f32_16x16x32_bf16(aq[kc], bk, sacc[nt], 0, 0, 0);
            }
        }
        // ---- scale + causal mask (diagonal tile only) ----
#pragma unroll
        for (int nt = 0; nt < 4; ++nt)
#pragma unroll
            for (int r = 0; r < 4; ++r) sacc[nt][r] *= 0.08838834764831845f;
        if (jt == qt) {
#pragma unroll
            for (int nt = 0; nt < 4; ++nt) {
                int colg = nt * 16 + l15;
#pragma unroll
                for (int r = 0; r < 4; ++r) {
                    int rowg = w * 16 + quad * 4 + r;
                    if (colg > rowg) sacc[nt][r] = -1e30f;
                }
            }
        }
        // ---- online softmax (registers + 16-lane shuffles) ----
        float alpha[4];
#pragma unroll
        for (int r = 0; r < 4; ++r) {
            float mx = fmaxf(fmaxf(sacc[0][r], sacc[1][r]), fmaxf(sacc[2][r], sacc[3][r]));
            mx = fmaxf(mx, __shfl_xor(mx, 1));
            mx = fmaxf(mx, __shfl_xor(mx, 2));
            mx = fmaxf(mx, __shfl_xor(mx, 4));
            mx = fmaxf(mx, __shfl_xor(mx, 8));
            float mn = fmaxf(m_st[r], mx);
            alpha[r] = __expf(m_st[r] - mn);
            m_st[r] = mn;
        }
        float lsum[4] = {0.f, 0.f, 0.f, 0.f};
#pragma unroll
        for (int nt = 0; nt < 4; ++nt)
#pragma unroll
            for (int r = 0; r < 4; ++r) {
                float e = __expf(sacc[nt][r] - m_st[r]);
                sacc[nt][r] = e;
                lsum[r] += e;
            }
#pragma unroll
        for (int r = 0; r < 4; ++r) {
            float s = lsum[r];
            s += __shfl_xor(s, 1);
            s += __shfl_xor(s, 2);
            s += __shfl_xor(s, 4);
            s += __shfl_xor(s, 8);
            l_st[r] = l_st[r] * alpha[r] + s;
        }
        // ---- P -> per-wave LDS (bf16), rescale O ----
#pragma unroll
        for (int nt = 0; nt < 4; ++nt)
#pragma unroll
            for (int r = 0; r < 4; ++r)
                P_lds[w][quad * 4 + r][nt * 16 + l15] = f2bf(sacc[nt][r]);
#pragma unroll
        for (int nt = 0; nt < 8; ++nt)
#pragma unroll
            for (int r = 0; r < 4; ++r) oacc[nt][r] *= alpha[r];
        // ---- stage Vt[buf] (single barrier per iter; j-2 readers fenced by j-1 barrier) ----
        __syncthreads();
#pragma unroll
        for (int it = 0; it < 4; ++it) {
            int u = tid + it * 256;
            int d = u >> 3, c8 = u & 7;
            *(short8*)&Vt[buf][d][c8 * 8] = vreg[it];
        }
        __syncthreads();
        // ---- O += P V : 8 d-tiles x 2 k-chunks ----
#pragma unroll
        for (int c = 0; c < 2; ++c) {
            short8 ap = *(const short8*)&P_lds[w][l15][c * 32 + quad * 8];
#pragma unroll
            for (int nt = 0; nt < 8; ++nt) {
                short8 bv = *(const short8*)&Vt[buf][nt * 16 + l15][c * 32 + quad * 8];
                oacc[nt] = __builtin_amdgcn_mfma_f32_16x16x32_bf16(ap, bv, oacc[nt], 0, 0, 0);
            }
        }
    }
    // ---- normalize, write per-group partial ----
#pragma unroll
    for (int r = 0; r < 4; ++r) {
        float inv = 1.f / l_st[r];
        int row = i0 + w * 16 + quad * 4 + r;
        float* dst = part + ((size_t)g * SEQ + row) * 1024 + h * 128;
#pragma unroll
        for (int nt = 0; nt < 8; ++nt) dst[nt * 16 + l15] = oacc[nt][r] * inv;
    }
}

// attn_bf[s][c] = bf16( sum_g part[g][s][c] )
__global__ void sum4_bf_kernel(const float* __restrict__ part, ushort_t* __restrict__ attn) {
    int idx = blockIdx.x * 256 + threadIdx.x;  // 524288 float4 units
    const float4* p = (const float4*)part;
    float4 a = p[idx];
    float4 b = p[idx + 524288];
    float4 c = p[idx + 2 * 524288];
    float4 d = p[idx + 3 * 524288];
    union { ushort_t u[4]; unsigned long long ll; } pk;
    pk.u[0] = f2bf(a.x + b.x + c.x + d.x);
    pk.u[1] = f2bf(a.y + b.y + c.y + d.y);
    pk.u[2] = f2bf(a.z + b.z + c.z + d.z);
    pk.u[3] = f2bf(a.w + b.w + c.w + d.w);
    *(unsigned long long*)&attn[(size_t)idx * 4] = pk.ll;
}

extern "C" void kernel_launch(void* const* d_in, const int* in_sizes, int n_in,
                              void* d_out, int out_size, void* d_ws, size_t ws_size,
                              hipStream_t stream) {
    const float* x  = (const float*)d_in[0];
    const float* Wq = (const float*)d_in[1];
    const float* bq = (const float*)d_in[2];
    const float* Wk = (const float*)d_in[3];
    const float* bk = (const float*)d_in[4];
    const float* Wv = (const float*)d_in[5];
    const float* bv = (const float*)d_in[6];
    const float* Wo = (const float*)d_in[7];
    const float* bo = (const float*)d_in[8];
    const float* W1 = (const float*)d_in[9];
    const float* b1 = (const float*)d_in[10];
    const float* W2 = (const float*)d_in[11];
    const float* b2 = (const float*)d_in[12];
    float* out = (float*)d_out;

    // Workspace layout (MB offsets), 54 MB total:
    //  0-8   q_f32  (dead after rope)  -> 0-4 attn_bf, 4-8 o_bf
    //  8-12  k_f32  (dead after rope)
    // 12-14  v_bf
    // 14-18  q_bf
    // 18-20  k_bf
    // 20-52  part f32 (dead after sum4) -> 20-36 h1_bf
    // 52-54  vT (bf16, [4][128][2048])
    char* ws = (char*)d_ws;
    float*    q_f32   = (float*)(ws);
    float*    k_f32   = (float*)(ws + ((size_t)8 << 20));
    ushort_t* v_bf    = (ushort_t*)(ws + ((size_t)12 << 20));
    ushort_t* q_bf    = (ushort_t*)(ws + ((size_t)14 << 20));
    ushort_t* k_bf    = (ushort_t*)(ws + ((size_t)18 << 20));
    float*    part    = (float*)(ws + ((size_t)20 << 20));
    ushort_t* attn_bf = (ushort_t*)(ws);
    ushort_t* o_bf    = (ushort_t*)(ws + ((size_t)4 << 20));
    ushort_t* h1_bf   = (ushort_t*)(ws + ((size_t)20 << 20));
    ushort_t* vT      = (ushort_t*)(ws + ((size_t)52 << 20));

    // q/k/v projections (fp32 in, bf16 MFMA, fp32/bf16 out)
    mfma_gemm_kernel<float, false, float><<<dim3(8, 16), 256, 0, stream>>>(
        x, Wq, bq, q_f32, SEQ, 1024, 1024);
    mfma_gemm_kernel<float, false, float><<<dim3(4, 16), 256, 0, stream>>>(
        x, Wk, bk, k_f32, SEQ, 512, 1024);
    mfma_gemm_kernel<float, false, ushort_t><<<dim3(4, 16), 256, 0, stream>>>(
        x, Wv, bv, v_bf, SEQ, 512, 1024);
    // V -> V^T ; RoPE -> bf16 q,k
    transpose_v_kernel<<<dim3(32, 8), 256, 0, stream>>>(v_bf, vT);
    rope_bf_kernel<<<SEQ, 256, 0, stream>>>(q_f32, k_f32, q_bf, k_bf);
    // flash attention + group sum
    mfma_attn_kernel<<<1024, 256, 0, stream>>>(q_bf, k_bf, vT, part);
    sum4_bf_kernel<<<2048, 256, 0, stream>>>(part, attn_bf);
    // output projection -> bf16 o
    mfma_gemm_kernel<ushort_t, false, ushort_t><<<dim3(8, 16), 256, 0, stream>>>(
        attn_bf, Wo, bo, o_bf, SEQ, 1024, 1024);
    // MLP: W1+SiLU -> bf16 h1 ; W2 -> fp32 out
    mfma_gemm_kernel<ushort_t, true, ushort_t><<<dim3(32, 16), 256, 0, stream>>>(
        o_bf, W1, b1, h1_bf, SEQ, 4096, 1024);
    mfma_gemm_kernel<ushort_t, false, float><<<dim3(32, 16), 256, 0, stream>>>(
        h1_bf, W2, b2, out, SEQ, 4096, 4096);
}